// Round 7
// baseline (1936.532 us; speedup 1.0000x reference)
//
#include <hip/hip_runtime.h>
#include <stdint.h>
#include <math.h>

// ---------------- problem constants ----------------
#define P_     4
#define L_     32
#define H_     1024
#define NE_    132          // (L_+1)*P_ embedding vectors
#define G4_    4096         // 4*H
#define TEMP_  5.0f
#define TANHC_ 2.5f
#define TINY_  1.1754943508222875e-38f   // jnp.finfo(f32).tiny

#define PRNG_PARTITIONABLE 1

// grid roles: blk 0 = master; 1..32 = fused a2+logits; 33..255 = workers (223)
#define NBLK   256
#define NTHR   512
#define NFUSE  32
#define WBASE  33

// ---------------- stamped-word + atomic helpers ----------------
__device__ __forceinline__ uint64_t pk(float v, uint32_t s) {
  union { float f; uint32_t u; } c; c.f = v;
  return ((uint64_t)s << 32) | c.u;
}
__device__ __forceinline__ float upk(uint64_t w) {
  union { uint32_t u; float f; } c; c.u = (uint32_t)w; return c.f;
}
__device__ __forceinline__ uint64_t ald64(const uint64_t* p) {
  return __hip_atomic_load(p, __ATOMIC_RELAXED, __HIP_MEMORY_SCOPE_AGENT);
}
__device__ __forceinline__ void ast64(uint64_t* p, uint64_t v) {
  __hip_atomic_store(p, v, __ATOMIC_RELAXED, __HIP_MEMORY_SCOPE_AGENT);
}
__device__ __forceinline__ void at_stf(float* p, float v) {
  __hip_atomic_store(p, v, __ATOMIC_RELAXED, __HIP_MEMORY_SCOPE_AGENT);
}
__device__ __forceinline__ int at_ldi(const int* p) {
  return __hip_atomic_load(p, __ATOMIC_RELAXED, __HIP_MEMORY_SCOPE_AGENT);
}
__device__ __forceinline__ void vmwait() {
  asm volatile("s_waitcnt vmcnt(0)" ::: "memory");
}

// ---------------- math helpers (verbatim FP order from r2/r5) -------------
__device__ __forceinline__ float wave_reduce_sum(float v) {
  for (int off = 32; off; off >>= 1) v += __shfl_xor(v, off);
  return v;
}
__device__ __forceinline__ float sigmoidf_(float x) {
  return 0.5f + 0.5f * tanhf(0.5f * x);   // XLA logistic-via-tanh
}
__device__ __forceinline__ void tf2x32(uint32_t k0, uint32_t k1,
                                       uint32_t& x0, uint32_t& x1) {
  uint32_t ks2 = k0 ^ k1 ^ 0x1BD11BDAu;
  x0 += k0; x1 += k1;
#define RR(r) { x0 += x1; x1 = (x1 << r) | (x1 >> (32 - r)); x1 ^= x0; }
  RR(13) RR(15) RR(26) RR(6)
  x0 += k1;  x1 += ks2 + 1u;
  RR(17) RR(29) RR(16) RR(24)
  x0 += ks2; x1 += k0 + 2u;
  RR(13) RR(15) RR(26) RR(6)
  x0 += k0;  x1 += k1 + 3u;
  RR(17) RR(29) RR(16) RR(24)
  x0 += k1;  x1 += ks2 + 4u;
  RR(13) RR(15) RR(26) RR(6)
  x0 += ks2; x1 += k0 + 5u;
#undef RR
}
__device__ __forceinline__ float dot_core(const float* __restrict__ wrow,
                                          const float* hv, int lane) {
  float acc = 0.f;
  for (int it = 0; it < 4; ++it) {
    float4 w4 = *(const float4*)(wrow + lane * 4 + it * 256);
    float4 h4 = *(const float4*)(hv   + lane * 4 + it * 256);
    acc += w4.x * h4.x + w4.y * h4.y + w4.z * h4.z + w4.w * h4.w;
  }
  return wave_reduce_sum(acc);
}
// 4 rows at once: all 16 weight loads issued before reductions (MLP x4).
// Per-row FP order identical to dot_core.
__device__ __forceinline__ void dot_core4(const float* __restrict__ wbase,
                                          size_t rstride,
                                          const float* hv, int lane,
                                          float o[4]) {
  float4 w[4][4]; float4 h4[4];
  for (int it = 0; it < 4; ++it) {
    int off = lane * 4 + it * 256;
    w[0][it] = *(const float4*)(wbase + off);
    w[1][it] = *(const float4*)(wbase + rstride + off);
    w[2][it] = *(const float4*)(wbase + 2 * rstride + off);
    w[3][it] = *(const float4*)(wbase + 3 * rstride + off);
    h4[it]   = *(const float4*)(hv + off);
  }
  for (int r = 0; r < 4; ++r) {
    float acc = 0.f;
    for (int it = 0; it < 4; ++it)
      acc += w[r][it].x * h4[it].x + w[r][it].y * h4[it].y
           + w[r][it].z * h4[it].z + w[r][it].w * h4[it].w;
    o[r] = wave_reduce_sum(acc);
  }
}

// ---------------- k_pre: Xp[p][e] = W_ih[p]@emb[e] + b_ih[p] + b_hh[p] ----
__global__ __launch_bounds__(256) void k_pre(const float* __restrict__ emb,
                                             const float* __restrict__ w_ih,
                                             const float* __restrict__ b_ih,
                                             const float* __restrict__ b_hh,
                                             float* __restrict__ Xp,
                                             int* __restrict__ adone) {
  int blk  = blockIdx.x;
  if (blk == 0 && threadIdx.x < 128) adone[threadIdx.x] = 0;
  int p    = blk >> 8;
  int rg   = blk & 255;
  int wave = threadIdx.x >> 6;
  int lane = threadIdx.x & 63;
  int r0   = rg * 16 + wave * 4;

  const float* wbase = w_ih + ((size_t)p * G4_ + r0) * H_;
  float4 Wr[4][4];
  for (int q = 0; q < 4; ++q)
    for (int it = 0; it < 4; ++it)
      Wr[q][it] = *(const float4*)(wbase + (size_t)q * H_ + lane * 4 + it * 256);
  float bias[4];
  for (int q = 0; q < 4; ++q)
    bias[q] = b_ih[p * G4_ + r0 + q] + b_hh[p * G4_ + r0 + q];

  for (int e = 0; e < NE_; ++e) {
    const float* ev = emb + (size_t)e * H_;
    float4 x[4];
    for (int it = 0; it < 4; ++it)
      x[it] = *(const float4*)(ev + lane * 4 + it * 256);
    for (int q = 0; q < 4; ++q) {
      float acc = 0.f;
      for (int it = 0; it < 4; ++it)
        acc += Wr[q][it].x * x[it].x + Wr[q][it].y * x[it].y
             + Wr[q][it].z * x[it].z + Wr[q][it].w * x[it].w;
      acc = wave_reduce_sum(acc);
      if (lane == 0)
        Xp[((size_t)p * NE_ + e) * G4_ + r0 + q] = acc + bias[q];
    }
  }
}

// ---------------- persistent kernel ----------------
struct KA {
  const float *Xp, *w_hh, *w_a1, *w_a2, *w_idx;
  const int* seed;
  uint64_t *hst;   // [4][1024] stamped h   (h-event ev -> slot ev&3, stamp ev+1)
  uint64_t *Gst;   // [4][4096] stamped W_hh@h (step s -> slot s&3, stamp s+1)
  float    *anc;   // [128][1024] anchors rows (plain values, agent stores)
  int      *adone; // [128] per-row completion counters (zeroed by k_pre)
  uint64_t *a2st;  // [1024] stamped anchor2 (stamp s+1)
  uint64_t *lst;   // [128]  stamped logits  (stamp s+1)
  float *out;      // [258]
};

__global__ __launch_bounds__(NTHR) void k_main(KA a) {
  const int blk  = blockIdx.x;
  const int tid  = threadIdx.x;
  const int wave = tid >> 6;
  const int lane = tid & 63;
  __shared__ __align__(16) float lds[4096];  // master: c[4][1024]; else h/a2
  __shared__ int sh_i;

  if (blk == 0) {
    // ====================== MASTER ======================
    for (int p = 0; p < P_; ++p) {
      const float* g = a.Xp + ((size_t)p * NE_ + (p * 33 + 32)) * G4_;
      for (int k = 0; k < 2; ++k) {
        int j = tid + k * 512;
        float c2 = sigmoidf_(g[j]) * tanhf(g[j + 2048]);
        float h2 = sigmoidf_(g[j + 3072]) * tanhf(c2);
        lds[p * H_ + j] = c2;
        ast64(a.hst + (size_t)p * H_ + j, pk(h2, p + 1));
      }
    }
    if (tid == 0) sh_i = 0;
    __syncthreads();

    float ent_acc = 0.f, lp_acc = 0.f;
    for (int s = 0; s < 128; ++s) {
      const int l = s >> 2, p = s & 3, n = 4 * (l + 1);
      const uint32_t st = (uint32_t)(s + 1);
      int idx = sh_i;
      int e = (l == 0) ? (p * 33 + 32) : ((idx & 3) * 33 + (idx >> 2));
      const float* xrow = a.Xp + ((size_t)p * NE_ + e) * G4_;
      const uint64_t* Gp = a.Gst + (size_t)p * G4_;

      uint64_t wv[8]; float xv[8]; float cold[2];
      for (int k = 0; k < 2; ++k) {
        int j = tid + k * 512;
        for (int q = 0; q < 4; ++q) {
          wv[k * 4 + q] = ald64(Gp + j + q * 1024);
          xv[k * 4 + q] = xrow[j + q * 1024];
        }
        cold[k] = lds[p * H_ + j];
      }
      for (int k = 0; k < 2; ++k)
        for (int q = 0; q < 4; ++q) {
          int j = tid + k * 512;
          while ((uint32_t)(wv[k * 4 + q] >> 32) != st)
            wv[k * 4 + q] = ald64(Gp + j + q * 1024);
        }
      __syncthreads();          // all G reads complete before any h' store
      for (int k = 0; k < 2; ++k) {
        int j = tid + k * 512;
        float gi = upk(wv[k * 4 + 0]) + xv[k * 4 + 0];
        float gf = upk(wv[k * 4 + 1]) + xv[k * 4 + 1];
        float gg = upk(wv[k * 4 + 2]) + xv[k * 4 + 2];
        float go = upk(wv[k * 4 + 3]) + xv[k * 4 + 3];
        float c2 = sigmoidf_(gf) * cold[k] + sigmoidf_(gi) * tanhf(gg);
        float h2 = sigmoidf_(go) * tanhf(c2);
        lds[p * H_ + j] = c2;
        ast64(a.hst + (size_t)p * H_ + j, pk(h2, (uint32_t)(s + 5)));
      }

      if (wave == 0) {
        uint64_t lw[2]; int ii[2]; float lg[2], sv[2];
        for (int k = 0; k < 2; ++k) {
          int i = lane + 64 * k; ii[k] = i;
          if (i < n) lw[k] = ald64(a.lst + i);
        }
        for (int k = 0; k < 2; ++k)
          if (ii[k] < n)
            while ((uint32_t)(lw[k] >> 32) != st) lw[k] = ald64(a.lst + ii[k]);
        uint32_t seed = (uint32_t)(*a.seed);
        uint32_t sk0 = 0u, sk1 = (uint32_t)s;
        tf2x32(0u, seed, sk0, sk1);
        for (int k = 0; k < 2; ++k) {
          int i = ii[k];
          if (i < n) {
#if PRNG_PARTITIONABLE
            uint32_t b0 = 0u, b1 = (uint32_t)i;
            tf2x32(sk0, sk1, b0, b1);
            uint32_t bits = b0 ^ b1;
#else
            int half = n >> 1;
            uint32_t c0 = (uint32_t)(i < half ? i : i - half);
            uint32_t c1 = (uint32_t)(i < half ? i + half : i);
            uint32_t r0 = c0, r1 = c1;
            tf2x32(sk0, sk1, r0, r1);
            uint32_t bits = (i < half) ? r0 : r1;
#endif
            uint32_t fb = (bits >> 9) | 0x3F800000u;
            float u = __uint_as_float(fb) - 1.0f;
            u = fmaxf(TINY_, u * (1.0f - TINY_) + TINY_);
            float g = -logf(-logf(u));
            lg[k] = upk(lw[k]);
            sv[k] = g + lg[k];
          } else { sv[k] = -INFINITY; lg[k] = -INFINITY; }
        }
        float bv; int bi;
        if (sv[0] >= sv[1]) { bv = sv[0]; bi = ii[0]; }
        else                { bv = sv[1]; bi = ii[1]; }
        for (int off = 32; off; off >>= 1) {
          float ov = __shfl_xor(bv, off);
          int   oi = __shfl_xor(bi, off);
          if (ov > bv || (ov == bv && oi < bi)) { bv = ov; bi = oi; }
        }
        float m = fmaxf(lg[0], lg[1]);
        for (int off = 32; off; off >>= 1) m = fmaxf(m, __shfl_xor(m, off));
        float se = 0.f;
        for (int k = 0; k < 2; ++k) if (ii[k] < n) se += expf(lg[k] - m);
        se = wave_reduce_sum(se);
        float lse = logf(se);
        float ent = 0.f;
        for (int k = 0; k < 2; ++k) if (ii[k] < n) {
          float lpv = (lg[k] - m) - lse;
          ent -= expf(lpv) * lpv;
        }
        ent = wave_reduce_sum(ent);
        if (lane == 0) {
          float li = upk(ald64(a.lst + bi));  // exact logits[bi]
          ent_acc += ent;
          lp_acc  += -((li - m) - lse);
          a.out[s]       = (float)(bi & 3);   // arch % P
          a.out[128 + s] = (float)(bi >> 2);  // arch // P
          sh_i = bi;
        }
      }
      __syncthreads();   // sh_i visible for next step
    }
    if (tid == 0) { a.out[256] = ent_acc; a.out[257] = lp_acc; }

  } else if (blk <= NFUSE) {
    // ====================== FUSED a2 + logits ======================
    const int fb = blk - 1;              // 0..31; owns a2 rows [32fb,32fb+32)
    float4 areg[4]; bool haveA = false;  // reg-cached anchors row (waves 0..3)
    const int rl = 4 * fb + wave;        // logits row for waves 0..3
    for (int s = 0; s < 128; ++s) {
      const int p = s & 3, n = 4 * ((s >> 2) + 1);
      const uint32_t st = (uint32_t)(s + 1);
      const uint32_t hs = (uint32_t)(s + 5);
      __syncthreads();                   // protect lds reuse across steps
      {
        const uint64_t* hp = a.hst + (size_t)p * H_;
        uint64_t w0 = ald64(hp + tid), w1 = ald64(hp + tid + 512);
        while ((uint32_t)(w0 >> 32) != hs) w0 = ald64(hp + tid);
        while ((uint32_t)(w1 >> 32) != hs) w1 = ald64(hp + tid + 512);
        lds[tid] = upk(w0); lds[tid + 512] = upk(w1);
      }
      __syncthreads();
      // four a2 rows per wave, batched (exact per-row dot order)
      {
        int r = fb * 32 + wave * 4;
        float o[4];
        dot_core4(a.w_a2 + ((size_t)p * H_ + r) * H_, H_, lds, lane, o);
        if (lane == 0)
          for (int q = 0; q < 4; ++q) ast64(a.a2st + r + q, pk(o[q], st));
      }
      bool active = (4 * fb) < n;        // block-uniform
      if (active) {
        if (wave < 4 && !haveA && rl < n) {
          while (at_ldi(a.adone + rl) < H_) __builtin_amdgcn_s_sleep(1);
          const float* ar = a.anc + (size_t)rl * H_;
          for (int it = 0; it < 4; ++it)
            areg[it] = *(const float4*)(ar + lane * 4 + it * 256);
          haveA = true;
        }
        {
          uint64_t w0 = ald64(a.a2st + tid), w1 = ald64(a.a2st + tid + 512);
          while ((uint32_t)(w0 >> 32) != st) w0 = ald64(a.a2st + tid);
          while ((uint32_t)(w1 >> 32) != st) w1 = ald64(a.a2st + tid + 512);
          lds[1024 + tid] = upk(w0); lds[1024 + tid + 512] = upk(w1);
        }
        __syncthreads();
        if (wave < 4 && rl < n) {        // exact r2 k4 math
          const float* wi = a.w_idx + p * H_;
          float acc = 0.f;
          for (int it = 0; it < 4; ++it) {
            float4 a4 = areg[it];
            float4 b4 = *(const float4*)(&lds[1024 + lane * 4 + it * 256]);
            float4 w4 = *(const float4*)(wi + lane * 4 + it * 256);
            acc += tanhf(a4.x + b4.x) * w4.x + tanhf(a4.y + b4.y) * w4.y
                 + tanhf(a4.z + b4.z) * w4.z + tanhf(a4.w + b4.w) * w4.w;
          }
          acc = wave_reduce_sum(acc);
          if (lane == 0) ast64(a.lst + rl, pk(TANHC_ * tanhf(acc / TEMP_), st));
        }
      }
    }

  } else {
    // ====================== WORKERS (path-stationary, 223 blocks) =========
    const int x  = blk - WBASE;          // 0..222
    const int p  = x & 3;
    const int w  = x >> 2;
    const int nw = (p < 3) ? 56 : 55;    // 56+56+56+55 = 223
    const int aLo = w * H_  / nw, aHi = (w + 1) * H_  / nw;
    const int gLo = w * G4_ / nw, gHi = (w + 1) * G4_ / nw;
    const float* wa = a.w_a1 + (size_t)p * H_  * H_;
    const float* wg = a.w_hh + (size_t)p * G4_ * H_;
    for (int ev = p; ev < 128; ev += 4) {
      const uint32_t st = (uint32_t)(ev + 1);
      const uint64_t* hp = a.hst + (size_t)(ev & 3) * H_;
      __syncthreads();
      {
        uint64_t w0 = ald64(hp + tid), w1 = ald64(hp + tid + 512);
        while ((uint32_t)(w0 >> 32) != st) {
          __builtin_amdgcn_s_sleep(1); w0 = ald64(hp + tid);
        }
        while ((uint32_t)(w1 >> 32) != st) {
          __builtin_amdgcn_s_sleep(1); w1 = ald64(hp + tid + 512);
        }
        lds[tid] = upk(w0); lds[tid + 512] = upk(w1);
      }
      __syncthreads();
      // anchors (1-step deadline) first, 4-row batches
      float* ad = a.anc + (size_t)ev * H_;
      for (int d = aLo + wave * 4; d < aHi; d += 32) {
        int m = aHi - d; m = m > 4 ? 4 : m;
        if (m == 4) {
          float o[4];
          dot_core4(wa + (size_t)d * H_, H_, lds, lane, o);
          if (lane == 0)
            for (int q = 0; q < 4; ++q) at_stf(ad + d + q, o[q]);
        } else {
          for (int q = 0; q < m; ++q) {
            float v = dot_core(wa + (size_t)(d + q) * H_, lds, lane);
            if (lane == 0) at_stf(ad + d + q, v);
          }
        }
      }
      vmwait();
      __syncthreads();
      if (tid == 0) atomicAdd(a.adone + ev, aHi - aLo);
      // G (4-step deadline), 4-row batches, self-stamped
      uint64_t* gd = a.Gst + (size_t)(ev & 3) * G4_;
      for (int d = gLo + wave * 4; d < gHi; d += 32) {
        int m = gHi - d; m = m > 4 ? 4 : m;
        if (m == 4) {
          float o[4];
          dot_core4(wg + (size_t)d * H_, H_, lds, lane, o);
          if (lane == 0)
            for (int q = 0; q < 4; ++q) ast64(gd + d + q, pk(o[q], st));
        } else {
          for (int q = 0; q < m; ++q) {
            float v = dot_core(wg + (size_t)(d + q) * H_, lds, lane);
            if (lane == 0) ast64(gd + d + q, pk(v, st));
          }
        }
      }
    }
  }
}

// ---------------- host ----------------
extern "C" void kernel_launch(void* const* d_in, const int* in_sizes, int n_in,
                              void* d_out, int out_size, void* d_ws, size_t ws_size,
                              hipStream_t stream) {
  (void)in_sizes; (void)n_in; (void)out_size; (void)ws_size;
  const float* emb   = (const float*)d_in[0];
  const float* w_ih  = (const float*)d_in[1];
  const float* w_hh  = (const float*)d_in[2];
  const float* b_ih  = (const float*)d_in[3];
  const float* b_hh  = (const float*)d_in[4];
  const float* w_a1  = (const float*)d_in[5];
  const float* w_a2  = (const float*)d_in[6];
  const float* w_idx = (const float*)d_in[7];
  const int*   seed  = (const int*)d_in[8];
  float* out = (float*)d_out;

  float* ws = (float*)d_ws;
  size_t o = 0;
  float*    Xp   = ws + o;              o += (size_t)P_ * NE_ * G4_; // 2,162,688
  uint64_t* hst  = (uint64_t*)(ws + o); o += 2 * 4 * H_;
  uint64_t* Gst  = (uint64_t*)(ws + o); o += 2 * 4 * G4_;
  float*    anc  = ws + o;              o += (size_t)128 * H_;
  uint64_t* a2st = (uint64_t*)(ws + o); o += 2 * H_;
  uint64_t* lst  = (uint64_t*)(ws + o); o += 2 * 128;
  int*      adn  = (int*)(ws + o);      o += 128;

  k_pre<<<1024, 256, 0, stream>>>(emb, w_ih, b_ih, b_hh, Xp, adn);

  KA ka;
  ka.Xp = Xp; ka.w_hh = w_hh; ka.w_a1 = w_a1; ka.w_a2 = w_a2; ka.w_idx = w_idx;
  ka.seed = seed;
  ka.hst = hst; ka.Gst = Gst; ka.anc = anc; ka.adone = adn;
  ka.a2st = a2st; ka.lst = lst; ka.out = out;

  void* kp[] = { (void*)&ka };
  hipLaunchCooperativeKernel((const void*)k_main, dim3(NBLK), dim3(NTHR),
                             kp, 0, stream);
}